// Round 4
// baseline (179.223 us; speedup 1.0000x reference)
//
#include <hip/hip_runtime.h>

#define SEQ 4096
#define DIM 1024
#define NH 16
#define HD 64
#define QKVSTR 3072

typedef __attribute__((ext_vector_type(8))) short bf16x8;
typedef __attribute__((ext_vector_type(4))) float f32x4;
typedef __attribute__((ext_vector_type(16))) float f32x16;
typedef __attribute__((ext_vector_type(4))) unsigned int uint4v;

__device__ __forceinline__ unsigned short f2bf(float f) {
  unsigned int b = __float_as_uint(f);
  b = b + 0x7fffu + ((b >> 16) & 1u);
  return (unsigned short)(b >> 16);
}

__device__ __forceinline__ unsigned int cvt_pk_bf16(float lo, float hi) {
  unsigned int r;
  asm("v_cvt_pk_bf16_f32 %0, %1, %2" : "=v"(r) : "v"(lo), "v"(hi));
  return r;
}

__device__ __forceinline__ float fast_exp2(float x) {
#if __has_builtin(__builtin_amdgcn_exp2f)
  return __builtin_amdgcn_exp2f(x);
#else
  float r; asm("v_exp_f32 %0, %1" : "=v"(r) : "v"(x)); return r;
#endif
}

typedef __attribute__((address_space(3))) unsigned int lds_uint;
typedef __attribute__((address_space(1))) const unsigned int global_uint;

__device__ __forceinline__ void gload_lds16(const void* g, void* l) {
  __builtin_amdgcn_global_load_lds((global_uint*)g, (lds_uint*)l, 16, 0, 0);
}

// ---------------- cast fp32 -> bf16 (x8 per thread), optional scale ----------------
__global__ __launch_bounds__(256) void cast_bf16_kernel(
    const float* __restrict__ in, unsigned short* __restrict__ out, int n8, float scale) {
  int i = blockIdx.x * blockDim.x + threadIdx.x;
  if (i >= n8) return;
  const float4* p = (const float4*)in + (size_t)i * 2;
  float4 x0 = p[0], x1 = p[1];
  union { unsigned short u[8]; uint4v v; } o;
  o.u[0] = f2bf(x0.x * scale); o.u[1] = f2bf(x0.y * scale);
  o.u[2] = f2bf(x0.z * scale); o.u[3] = f2bf(x0.w * scale);
  o.u[4] = f2bf(x1.x * scale); o.u[5] = f2bf(x1.y * scale);
  o.u[6] = f2bf(x1.z * scale); o.u[7] = f2bf(x1.w * scale);
  *((uint4v*)out + i) = o.v;
}

// ---------------- GEMM: C[M,N] = A[M,K](bf16) @ B[N,K]^T(bf16) (+bias) ----------------
// BIASMODE: 0 = none, 1 = qkv select (bq*QSCALE / 0 / bv), 2 = single bias b0
template<int BIASMODE, int OUT_F32>
__global__ __launch_bounds__(256) void gemm_bt_kernel(
    const unsigned short* __restrict__ A, const unsigned short* __restrict__ B,
    const float* __restrict__ b0, const float* __restrict__ b1, float qscale,
    void* __restrict__ Cout, int M, int N, int K) {
  __shared__ unsigned short As[128 * 32];
  __shared__ unsigned short Bs[128 * 32];
  int tid = threadIdx.x;
  int wave = tid >> 6, lane = tid & 63;
  int g = lane >> 4, lc = lane & 15;
  int wm = wave >> 1, wn = wave & 1;
  int m0 = blockIdx.y * 128, n0 = blockIdx.x * 128;

  f32x4 acc[4][4] = {};

  for (int k0 = 0; k0 < K; k0 += 32) {
    __syncthreads();
    for (int c = 0; c < 2; ++c) {
      int chunk = c * 256 + wave * 64 + lane;
      int row = chunk >> 2, cb = chunk & 3;
      gload_lds16(A + (size_t)(m0 + row) * K + k0 + cb * 8, As + (c * 256 + wave * 64) * 8);
      gload_lds16(B + (size_t)(n0 + row) * K + k0 + cb * 8, Bs + (c * 256 + wave * 64) * 8);
    }
    __syncthreads();
    bf16x8 af[4], bfr[4];
    for (int mf = 0; mf < 4; ++mf)
      af[mf] = *(const bf16x8*)&As[(wm * 64 + mf * 16 + lc) * 32 + g * 8];
    for (int nf = 0; nf < 4; ++nf)
      bfr[nf] = *(const bf16x8*)&Bs[(wn * 64 + nf * 16 + lc) * 32 + g * 8];
    for (int mf = 0; mf < 4; ++mf)
      for (int nf = 0; nf < 4; ++nf)
        acc[mf][nf] = __builtin_amdgcn_mfma_f32_16x16x32_bf16(af[mf], bfr[nf], acc[mf][nf], 0, 0, 0);
  }

  for (int nf = 0; nf < 4; ++nf) {
    int col = n0 + wn * 64 + nf * 16 + lc;
    float bias = 0.f;
    if (BIASMODE == 1) {
      int sect = col >> 10, cc = col & 1023;
      bias = (sect == 0) ? b0[cc] * qscale : ((sect == 2) ? b1[cc] : 0.f);
    } else if (BIASMODE == 2) {
      bias = b0[col];
    }
    for (int mf = 0; mf < 4; ++mf) {
      int row = m0 + wm * 64 + mf * 16 + g * 4;
      for (int r = 0; r < 4; ++r) {
        float v = acc[mf][nf][r] + bias;
        if (OUT_F32) ((float*)Cout)[(size_t)(row + r) * N + col] = v;
        else ((unsigned short*)Cout)[(size_t)(row + r) * N + col] = f2bf(v);
      }
    }
  }
}

// ---------------- V transpose: V (rows of QKV, stride 3072) -> Vt[D][S] ----------------
__global__ __launch_bounds__(256) void transpose_kernel(
    const unsigned short* __restrict__ V, unsigned short* __restrict__ Vt) {
  __shared__ unsigned short Ts[64 * 72];
  int tid = threadIdx.x;
  int s0 = blockIdx.x * 64, d0 = blockIdx.y * 64;
  for (int c = 0; c < 2; ++c) {
    int q = c * 256 + tid;
    int r = q >> 3, cb = q & 7;
    uint4v v = *(const uint4v*)&V[(size_t)(s0 + r) * QKVSTR + d0 + cb * 8];
    *(uint4v*)&Ts[r * 72 + cb * 8] = v;
  }
  __syncthreads();
  for (int c = 0; c < 2; ++c) {
    int q = c * 256 + tid;
    int d = q >> 3, sc = q & 7;
    union { unsigned short u[8]; uint4v v; } ov;
    for (int j = 0; j < 8; ++j) ov.u[j] = Ts[(sc * 8 + j) * 72 + d];
    *(uint4v*)&Vt[(size_t)(d0 + d) * SEQ + s0 + sc * 8] = ov.v;
  }
}

// ---------------- flash attention, swapped-QK 32x32, counted-vmcnt pipeline ----------------
// Q pre-scaled by 0.125*log2(e) (folded into Wq/bq) -> exp2 directly.
// No-max softmax, deferred li reduce. T3/T4: prefetch stays in flight across
// raw s_barriers, vmcnt(4) only (never 0). T5: setprio around MFMA clusters.
// T1: XCD head-chunked swizzle (2 heads per XCD -> K/V fits 4MB L2).
__global__ __launch_bounds__(256) void attn_kernel(
    const unsigned short* __restrict__ QKV, const unsigned short* __restrict__ Vt,
    unsigned short* __restrict__ Aout) {
  __shared__ unsigned short Qs[128 * 64];
  __shared__ unsigned short Ks[2][64 * 64];
  __shared__ unsigned short Vs[2][64 * 64];
  int tid = threadIdx.x;
  int w = tid >> 6, lane = tid & 63;
  int hi = lane >> 5, l31 = lane & 31;

  // XCD swizzle: 512 blocks, 8 XCDs -> XCD x owns swz [64x,64x+64) = heads 2x..2x+1
  int bid = blockIdx.x;
  int swz = (bid & 7) * 64 + (bid >> 3);
  int h = swz >> 5;
  int q0 = (swz & 31) * 128;

  const unsigned short* Qg = QKV + h * HD;
  const unsigned short* Kg = QKV + DIM + h * HD;
  const unsigned short* Vg = Vt + (size_t)(h * HD) * SEQ;

  // loop-invariant per-lane staging offsets (chunk = c*256 + w*64 + lane)
  int ch0 = w * 64 + lane;
  int r0s = ch0 >> 3, d0s = (ch0 & 7) ^ (r0s & 7);
  int ch1 = 256 + ch0;
  int r1s = ch1 >> 3, d1s = (ch1 & 7) ^ (r1s & 7);
  int koff0 = r0s * QKVSTR + d0s * 8;
  int koff1 = r1s * QKVSTR + d1s * 8;
  int voff0 = r0s * SEQ + d0s * 8;
  int voff1 = r1s * SEQ + d1s * 8;
  unsigned short* ldsK_lo[2] = { &Ks[0][(w * 64) * 8],       &Ks[1][(w * 64) * 8] };
  unsigned short* ldsK_hi[2] = { &Ks[0][(256 + w * 64) * 8], &Ks[1][(256 + w * 64) * 8] };
  unsigned short* ldsV_lo[2] = { &Vs[0][(w * 64) * 8],       &Vs[1][(w * 64) * 8] };
  unsigned short* ldsV_hi[2] = { &Vs[0][(256 + w * 64) * 8], &Vs[1][(256 + w * 64) * 8] };

  // stage Q [128][64], XOR-swizzled via pre-swizzled global source (4 loads)
  for (int c = 0; c < 4; ++c) {
    int chunk = c * 256 + w * 64 + lane;
    int row = chunk >> 3, pos = chunk & 7;
    int db = pos ^ (row & 7);
    gload_lds16(Qg + (size_t)(q0 + row) * QKVSTR + db * 8, Qs + (c * 256 + w * 64) * 8);
  }
  // stage K/V tile 0 (4 loads) -> 8 outstanding
  {
    const unsigned short* Kt = Kg;
    const unsigned short* Vtt = Vg;
    gload_lds16(Kt + koff0, ldsK_lo[0]);
    gload_lds16(Kt + koff1, ldsK_hi[0]);
    gload_lds16(Vtt + voff0, ldsV_lo[0]);
    gload_lds16(Vtt + voff1, ldsV_hi[0]);
  }
  asm volatile("s_waitcnt vmcnt(4)" ::: "memory");  // Q done; tile0 in flight
  __builtin_amdgcn_sched_barrier(0);
  __builtin_amdgcn_s_barrier();

  // Q fragments in registers (B-operand: col q = l31, k = d)
  bf16x8 qf[4];
  {
    int qrow = w * 32 + l31;
    for (int dc = 0; dc < 4; ++dc) {
      int pos = 2 * dc + hi;
      qf[dc] = *(const bf16x8*)&Qs[qrow * 64 + (pos ^ (qrow & 7)) * 8];
    }
  }

  f32x16 o0 = {}, o1 = {};
  float lsum = 0.f;
  int cur = 0;

  for (int t = 0; t < SEQ / 64; ++t) {
    // prefetch tile t+1 (wraps to 0 on last iter to keep vmcnt invariant)
    {
      int kvn = ((t + 1) & (SEQ / 64 - 1)) * 64;
      const unsigned short* Kt = Kg + (size_t)kvn * QKVSTR;
      const unsigned short* Vtt = Vg + kvn;
      int nb = cur ^ 1;
      gload_lds16(Kt + koff0, ldsK_lo[nb]);
      gload_lds16(Kt + koff1, ldsK_hi[nb]);
      gload_lds16(Vtt + voff0, ldsV_lo[nb]);
      gload_lds16(Vtt + voff1, ldsV_hi[nb]);
    }
    asm volatile("s_waitcnt vmcnt(4)" ::: "memory");  // tile t resident (ours)
    __builtin_amdgcn_sched_barrier(0);
    __builtin_amdgcn_s_barrier();                     // tile t resident (all waves)
    __builtin_amdgcn_sched_barrier(0);

    // K fragments (A-operand: row kv = f*32+l31, k = d)
    bf16x8 kf[2][4];
    for (int f = 0; f < 2; ++f)
      for (int dc = 0; dc < 4; ++dc) {
        int krow = f * 32 + l31;
        int pos = 2 * dc + hi;
        kf[f][dc] = *(const bf16x8*)&Ks[cur][krow * 64 + (pos ^ (krow & 7)) * 8];
      }
    f32x16 st0 = {}, st1 = {};
    __builtin_amdgcn_s_setprio(1);
    for (int dc = 0; dc < 4; ++dc) {
      st0 = __builtin_amdgcn_mfma_f32_32x32x16_bf16(kf[0][dc], qf[dc], st0, 0, 0, 0);
      st1 = __builtin_amdgcn_mfma_f32_32x32x16_bf16(kf[1][dc], qf[dc], st1, 0, 0, 0);
    }
    __builtin_amdgcn_s_setprio(0);

    // V fragments early (latency hides under exp/pack)
    bf16x8 vf0[4], vf1[4];
#pragma unroll
    for (int c = 0; c < 4; ++c) {
      int pos = 2 * c + hi;
      int r0 = l31, r1 = 32 + l31;
      vf0[c] = *(const bf16x8*)&Vs[cur][r0 * 64 + (pos ^ (r0 & 7)) * 8];
      vf1[c] = *(const bf16x8*)&Vs[cur][r1 * 64 + (pos ^ (r1 & 7)) * 8];
    }

    // P = exp2(S^T) in-register; accumulate per-lane partial row-sum
    float p0[16], p1[16];
    float ls = 0.f;
#pragma unroll
    for (int r = 0; r < 16; ++r) { p0[r] = fast_exp2(st0[r]); ls += p0[r]; }
#pragma unroll
    for (int r = 0; r < 16; ++r) { p1[r] = fast_exp2(st1[r]); ls += p1[r]; }
    lsum += ls;

    // pack to bf16 + permlane32_swap -> PV A-frags pa[c] (T12)
    bf16x8 pa[4];
#pragma unroll
    for (int f = 0; f < 2; ++f) {
      const float* pp = f ? p1 : p0;
#pragma unroll
      for (int cc = 0; cc < 2; ++cc) {
        unsigned uLO0 = cvt_pk_bf16(pp[8 * cc + 0], pp[8 * cc + 1]);
        unsigned uLO1 = cvt_pk_bf16(pp[8 * cc + 2], pp[8 * cc + 3]);
        unsigned uHI0 = cvt_pk_bf16(pp[8 * cc + 4], pp[8 * cc + 5]);
        unsigned uHI1 = cvt_pk_bf16(pp[8 * cc + 6], pp[8 * cc + 7]);
        auto s0 = __builtin_amdgcn_permlane32_swap(uLO0, uHI0, false, false);
        auto s1 = __builtin_amdgcn_permlane32_swap(uLO1, uHI1, false, false);
        union { unsigned u[4]; bf16x8 v; } pw;
        pw.u[0] = s0[0]; pw.u[1] = s1[0]; pw.u[2] = s0[1]; pw.u[3] = s1[1];
        pa[f * 2 + cc] = pw.v;
      }
    }

    // PV
    __builtin_amdgcn_s_setprio(1);
#pragma unroll
    for (int c = 0; c < 4; ++c) {
      o0 = __builtin_amdgcn_mfma_f32_32x32x16_bf16(pa[c], vf0[c], o0, 0, 0, 0);
      o1 = __builtin_amdgcn_mfma_f32_32x32x16_bf16(pa[c], vf1[c], o1, 0, 0, 0);
    }
    __builtin_amdgcn_s_setprio(0);

    asm volatile("" ::: "memory");
    __builtin_amdgcn_sched_barrier(0);
    __builtin_amdgcn_s_barrier();   // all reads of tile t done -> next stage may overwrite
    cur ^= 1;
  }

  // finalize: one cross-half reduce for li, broadcast 1/li per C-row, store
  lsum += __shfl_xor(lsum, 32);
  float inv = 1.f / lsum;  // valid for q = l31 (both halves)
#pragma unroll
  for (int r = 0; r < 16; ++r) {
    int qr = (r & 3) + 8 * (r >> 2) + 4 * hi;
    float ir = __shfl(inv, qr + (lane & 32));
    size_t row = q0 + w * 32 + qr;
    Aout[row * DIM + h * HD + l31]      = f2bf(o0[r] * ir);
    Aout[row * DIM + h * HD + 32 + l31] = f2bf(o1[r] * ir);
  }
}

extern "C" void kernel_launch(void* const* d_in, const int* in_sizes, int n_in,
                              void* d_out, int out_size, void* d_ws, size_t ws_size,
                              hipStream_t stream) {
  (void)in_sizes; (void)n_in; (void)out_size; (void)ws_size;
  const float* X  = (const float*)d_in[0];
  const float* wq = (const float*)d_in[1];
  const float* bq = (const float*)d_in[2];
  const float* wk = (const float*)d_in[3];
  const float* wv = (const float*)d_in[4];
  const float* bv = (const float*)d_in[5];
  const float* wo = (const float*)d_in[6];
  const float* bo = (const float*)d_in[7];

  char* ws = (char*)d_ws;
  const size_t SZ_XD  = (size_t)SEQ * DIM * 2;      // 8 MB
  const size_t SZ_W   = (size_t)DIM * DIM * 2;      // 2 MB
  const size_t SZ_QKV = (size_t)SEQ * QKVSTR * 2;   // 24 MB
  unsigned short* Xb   = (unsigned short*)(ws);                    // reused as Ab
  unsigned short* Wqkv = (unsigned short*)(ws + SZ_XD);            // [3072][1024]
  unsigned short* Wob  = (unsigned short*)(ws + SZ_XD + 3 * SZ_W);
  unsigned short* QKVb = (unsigned short*)(ws + SZ_XD + 4 * SZ_W); // [4096][3072]
  unsigned short* Vtb  = (unsigned short*)(ws + SZ_XD + 4 * SZ_W + SZ_QKV);
  unsigned short* Ab   = Xb;

  const float QSCALE = 0.125f * 1.44269504088896f;  // fold 1/sqrt(hd) * log2(e) into Wq/bq
  int nX8 = SEQ * DIM / 8, nW8 = DIM * DIM / 8;
  cast_bf16_kernel<<<nX8 / 256, 256, 0, stream>>>(X,  Xb, nX8, 1.f);
  cast_bf16_kernel<<<nW8 / 256, 256, 0, stream>>>(wq, Wqkv,                nW8, QSCALE);
  cast_bf16_kernel<<<nW8 / 256, 256, 0, stream>>>(wk, Wqkv + (size_t)DIM * DIM,     nW8, 1.f);
  cast_bf16_kernel<<<nW8 / 256, 256, 0, stream>>>(wv, Wqkv + (size_t)2 * DIM * DIM, nW8, 1.f);
  cast_bf16_kernel<<<nW8 / 256, 256, 0, stream>>>(wo, Wob, nW8, 1.f);

  // fused QKV projection: [4096][3072] bf16
  gemm_bt_kernel<1, 0><<<dim3(QKVSTR / 128, SEQ / 128), 256, 0, stream>>>(
      Xb, Wqkv, bq, bv, QSCALE, QKVb, SEQ, QKVSTR, DIM);

  // V^T: [1024][4096]
  transpose_kernel<<<dim3(SEQ / 64, DIM / 64), 256, 0, stream>>>(QKVb + 2 * DIM, Vtb);

  attn_kernel<<<SEQ / 128 * NH, 256, 0, stream>>>(QKVb, Vtb, Ab);

  // output projection (f32 out)
  gemm_bt_kernel<2, 1><<<dim3(DIM / 128, SEQ / 128), 256, 0, stream>>>(
      Ab, Wob, bo, nullptr, 1.f, d_out, SEQ, DIM, DIM);
}

// Round 6
// 170.765 us; speedup vs baseline: 1.0495x; 1.0495x over previous
//
#include <hip/hip_runtime.h>

#define SEQ 4096
#define DIM 1024
#define NH 16
#define HD 64
#define QKVSTR 3072

typedef __attribute__((ext_vector_type(8))) short bf16x8;
typedef __attribute__((ext_vector_type(4))) float f32x4;
typedef __attribute__((ext_vector_type(16))) float f32x16;
typedef __attribute__((ext_vector_type(4))) unsigned int uint4v;

__device__ __forceinline__ unsigned short f2bf(float f) {
  unsigned int b = __float_as_uint(f);
  b = b + 0x7fffu + ((b >> 16) & 1u);
  return (unsigned short)(b >> 16);
}

__device__ __forceinline__ unsigned int cvt_pk_bf16(float lo, float hi) {
  unsigned int r;
  asm("v_cvt_pk_bf16_f32 %0, %1, %2" : "=v"(r) : "v"(lo), "v"(hi));
  return r;
}

__device__ __forceinline__ float fast_exp2(float x) {
#if __has_builtin(__builtin_amdgcn_exp2f)
  return __builtin_amdgcn_exp2f(x);
#else
  float r; asm("v_exp_f32 %0, %1" : "=v"(r) : "v"(x)); return r;
#endif
}

typedef __attribute__((address_space(3))) unsigned int lds_uint;
typedef __attribute__((address_space(1))) const unsigned int global_uint;

__device__ __forceinline__ void gload_lds16(const void* g, void* l) {
  __builtin_amdgcn_global_load_lds((global_uint*)g, (lds_uint*)l, 16, 0, 0);
}

// ---------------- fused cast fp32 -> bf16 for all 5 tensors (1 launch) ----------------
// group-of-8 boundaries (all block-aligned at 256 threads):
// X [0,524288) -> Xb ; wq [524288,655360) -> Wqkv (xQSCALE) ; wk -> +1M ; wv -> +2M ; wo -> Wob
__global__ __launch_bounds__(256) void cast_all_kernel(
    const float* __restrict__ X, const float* __restrict__ wq, const float* __restrict__ wk,
    const float* __restrict__ wv, const float* __restrict__ wo,
    unsigned short* __restrict__ Xb, unsigned short* __restrict__ Wqkv,
    unsigned short* __restrict__ Wob, float qscale) {
  int i = blockIdx.x * 256 + threadIdx.x;
  const float* src;
  unsigned short* dst;
  float sc = 1.f;
  if (i < 524288) { src = X + (size_t)i * 8; dst = Xb + (size_t)i * 8; }
  else if (i < 655360) { int j = i - 524288; src = wq + (size_t)j * 8; dst = Wqkv + (size_t)j * 8; sc = qscale; }
  else if (i < 786432) { int j = i - 655360; src = wk + (size_t)j * 8; dst = Wqkv + 1048576 + (size_t)j * 8; }
  else if (i < 917504) { int j = i - 786432; src = wv + (size_t)j * 8; dst = Wqkv + 2097152 + (size_t)j * 8; }
  else { int j = i - 917504; src = wo + (size_t)j * 8; dst = Wob + (size_t)j * 8; }
  const float4* p = (const float4*)src;
  float4 x0 = p[0], x1 = p[1];
  union { unsigned short u[8]; uint4v v; } o;
  o.u[0] = f2bf(x0.x * sc); o.u[1] = f2bf(x0.y * sc);
  o.u[2] = f2bf(x0.z * sc); o.u[3] = f2bf(x0.w * sc);
  o.u[4] = f2bf(x1.x * sc); o.u[5] = f2bf(x1.y * sc);
  o.u[6] = f2bf(x1.z * sc); o.u[7] = f2bf(x1.w * sc);
  *(uint4v*)dst = o.v;
}

// ---------------- GEMM: C[M,N] = A[M,K](bf16) @ B[N,K]^T(bf16) (+bias) ----------------
// BIASMODE: 0 = none, 1 = qkv select (bq*QSCALE / 0 / bv), 2 = single bias b0
template<int BIASMODE, int OUT_F32>
__global__ __launch_bounds__(256) void gemm_bt_kernel(
    const unsigned short* __restrict__ A, const unsigned short* __restrict__ B,
    const float* __restrict__ b0, const float* __restrict__ b1, float qscale,
    void* __restrict__ Cout, int M, int N, int K) {
  __shared__ unsigned short As[128 * 32];
  __shared__ unsigned short Bs[128 * 32];
  int tid = threadIdx.x;
  int wave = tid >> 6, lane = tid & 63;
  int g = lane >> 4, lc = lane & 15;
  int wm = wave >> 1, wn = wave & 1;
  int m0 = blockIdx.y * 128, n0 = blockIdx.x * 128;

  f32x4 acc[4][4] = {};

  for (int k0 = 0; k0 < K; k0 += 32) {
    __syncthreads();
    for (int c = 0; c < 2; ++c) {
      int chunk = c * 256 + wave * 64 + lane;
      int row = chunk >> 2, cb = chunk & 3;
      gload_lds16(A + (size_t)(m0 + row) * K + k0 + cb * 8, As + (c * 256 + wave * 64) * 8);
      gload_lds16(B + (size_t)(n0 + row) * K + k0 + cb * 8, Bs + (c * 256 + wave * 64) * 8);
    }
    __syncthreads();
    bf16x8 af[4], bfr[4];
    for (int mf = 0; mf < 4; ++mf)
      af[mf] = *(const bf16x8*)&As[(wm * 64 + mf * 16 + lc) * 32 + g * 8];
    for (int nf = 0; nf < 4; ++nf)
      bfr[nf] = *(const bf16x8*)&Bs[(wn * 64 + nf * 16 + lc) * 32 + g * 8];
    for (int mf = 0; mf < 4; ++mf)
      for (int nf = 0; nf < 4; ++nf)
        acc[mf][nf] = __builtin_amdgcn_mfma_f32_16x16x32_bf16(af[mf], bfr[nf], acc[mf][nf], 0, 0, 0);
  }

  for (int nf = 0; nf < 4; ++nf) {
    int col = n0 + wn * 64 + nf * 16 + lc;
    float bias = 0.f;
    if (BIASMODE == 1) {
      int sect = col >> 10, cc = col & 1023;
      bias = (sect == 0) ? b0[cc] * qscale : ((sect == 2) ? b1[cc] : 0.f);
    } else if (BIASMODE == 2) {
      bias = b0[col];
    }
    for (int mf = 0; mf < 4; ++mf) {
      int row = m0 + wm * 64 + mf * 16 + g * 4;
      for (int r = 0; r < 4; ++r) {
        float v = acc[mf][nf][r] + bias;
        if (OUT_F32) ((float*)Cout)[(size_t)(row + r) * N + col] = v;
        else ((unsigned short*)Cout)[(size_t)(row + r) * N + col] = f2bf(v);
      }
    }
  }
}

// ---------------- V transpose: V (rows of QKV, stride 3072) -> Vt[D][S] ----------------
__global__ __launch_bounds__(256) void transpose_kernel(
    const unsigned short* __restrict__ V, unsigned short* __restrict__ Vt) {
  __shared__ unsigned short Ts[64 * 72];
  int tid = threadIdx.x;
  int s0 = blockIdx.x * 64, d0 = blockIdx.y * 64;
  for (int c = 0; c < 2; ++c) {
    int q = c * 256 + tid;
    int r = q >> 3, cb = q & 7;
    uint4v v = *(const uint4v*)&V[(size_t)(s0 + r) * QKVSTR + d0 + cb * 8];
    *(uint4v*)&Ts[r * 72 + cb * 8] = v;
  }
  __syncthreads();
  for (int c = 0; c < 2; ++c) {
    int q = c * 256 + tid;
    int d = q >> 3, sc = q & 7;
    union { unsigned short u[8]; uint4v v; } ov;
    for (int j = 0; j < 8; ++j) ov.u[j] = Ts[(sc * 8 + j) * 72 + d];
    *(uint4v*)&Vt[(size_t)(d0 + d) * SEQ + s0 + sc * 8] = ov.v;
  }
}

// ---------------- flash attention, swapped-QK 32x32, counted-vmcnt pipeline ----------------
// R4-proven body (2 buffers, 2 barriers/tile). Q pre-scaled by 0.125*log2(e)
// -> exp2 directly. No-max softmax, deferred li reduce. Prefetch stays in
// flight across raw s_barriers, vmcnt(4) only (never 0). setprio around MFMA.
// XCD head-chunked swizzle (2 heads per XCD -> K/V fits 4MB L2).
__global__ __launch_bounds__(256) void attn_kernel(
    const unsigned short* __restrict__ QKV, const unsigned short* __restrict__ Vt,
    unsigned short* __restrict__ Aout) {
  __shared__ unsigned short Qs[128 * 64];
  __shared__ unsigned short Ks[2][64 * 64];
  __shared__ unsigned short Vs[2][64 * 64];
  int tid = threadIdx.x;
  int w = tid >> 6, lane = tid & 63;
  int hi = lane >> 5, l31 = lane & 31;

  // XCD swizzle: 512 blocks, 8 XCDs -> XCD x owns swz [64x,64x+64) = heads 2x..2x+1
  int bid = blockIdx.x;
  int swz = (bid & 7) * 64 + (bid >> 3);
  int h = swz >> 5;
  int q0 = (swz & 31) * 128;

  const unsigned short* Qg = QKV + h * HD;
  const unsigned short* Kg = QKV + DIM + h * HD;
  const unsigned short* Vg = Vt + (size_t)(h * HD) * SEQ;

  // loop-invariant per-lane staging offsets (chunk = c*256 + w*64 + lane)
  int ch0 = w * 64 + lane;
  int r0s = ch0 >> 3, d0s = (ch0 & 7) ^ (r0s & 7);
  int ch1 = 256 + ch0;
  int r1s = ch1 >> 3, d1s = (ch1 & 7) ^ (r1s & 7);
  int koff0 = r0s * QKVSTR + d0s * 8;
  int koff1 = r1s * QKVSTR + d1s * 8;
  int voff0 = r0s * SEQ + d0s * 8;
  int voff1 = r1s * SEQ + d1s * 8;
  unsigned short* ldsK_lo[2] = { &Ks[0][(w * 64) * 8],       &Ks[1][(w * 64) * 8] };
  unsigned short* ldsK_hi[2] = { &Ks[0][(256 + w * 64) * 8], &Ks[1][(256 + w * 64) * 8] };
  unsigned short* ldsV_lo[2] = { &Vs[0][(w * 64) * 8],       &Vs[1][(w * 64) * 8] };
  unsigned short* ldsV_hi[2] = { &Vs[0][(256 + w * 64) * 8], &Vs[1][(256 + w * 64) * 8] };

  // stage Q [128][64], XOR-swizzled via pre-swizzled global source (4 loads)
  for (int c = 0; c < 4; ++c) {
    int chunk = c * 256 + w * 64 + lane;
    int row = chunk >> 3, pos = chunk & 7;
    int db = pos ^ (row & 7);
    gload_lds16(Qg + (size_t)(q0 + row) * QKVSTR + db * 8, Qs + (c * 256 + w * 64) * 8);
  }
  // stage K/V tile 0 (4 loads) -> 8 outstanding
  {
    const unsigned short* Kt = Kg;
    const unsigned short* Vtt = Vg;
    gload_lds16(Kt + koff0, ldsK_lo[0]);
    gload_lds16(Kt + koff1, ldsK_hi[0]);
    gload_lds16(Vtt + voff0, ldsV_lo[0]);
    gload_lds16(Vtt + voff1, ldsV_hi[0]);
  }
  asm volatile("s_waitcnt vmcnt(4)" ::: "memory");  // Q done; tile0 in flight
  __builtin_amdgcn_sched_barrier(0);
  __builtin_amdgcn_s_barrier();

  // Q fragments in registers (B-operand: col q = l31, k = d)
  bf16x8 qf[4];
  {
    int qrow = w * 32 + l31;
    for (int dc = 0; dc < 4; ++dc) {
      int pos = 2 * dc + hi;
      qf[dc] = *(const bf16x8*)&Qs[qrow * 64 + (pos ^ (qrow & 7)) * 8];
    }
  }

  f32x16 o0 = {}, o1 = {};
  float lsum = 0.f;
  int cur = 0;

  for (int t = 0; t < SEQ / 64; ++t) {
    // prefetch tile t+1 (wraps to 0 on last iter to keep vmcnt invariant)
    {
      int kvn = ((t + 1) & (SEQ / 64 - 1)) * 64;
      const unsigned short* Kt = Kg + (size_t)kvn * QKVSTR;
      const unsigned short* Vtt = Vg + kvn;
      int nb = cur ^ 1;
      gload_lds16(Kt + koff0, ldsK_lo[nb]);
      gload_lds16(Kt + koff1, ldsK_hi[nb]);
      gload_lds16(Vtt + voff0, ldsV_lo[nb]);
      gload_lds16(Vtt + voff1, ldsV_hi[nb]);
    }
    asm volatile("s_waitcnt vmcnt(4)" ::: "memory");  // tile t resident (ours)
    __builtin_amdgcn_sched_barrier(0);
    __builtin_amdgcn_s_barrier();                     // tile t resident (all waves)
    __builtin_amdgcn_sched_barrier(0);

    // K fragments (A-operand: row kv = f*32+l31, k = d)
    bf16x8 kf[2][4];
    for (int f = 0; f < 2; ++f)
      for (int dc = 0; dc < 4; ++dc) {
        int krow = f * 32 + l31;
        int pos = 2 * dc + hi;
        kf[f][dc] = *(const bf16x8*)&Ks[cur][krow * 64 + (pos ^ (krow & 7)) * 8];
      }
    f32x16 st0 = {}, st1 = {};
    __builtin_amdgcn_s_setprio(1);
    for (int dc = 0; dc < 4; ++dc) {
      st0 = __builtin_amdgcn_mfma_f32_32x32x16_bf16(kf[0][dc], qf[dc], st0, 0, 0, 0);
      st1 = __builtin_amdgcn_mfma_f32_32x32x16_bf16(kf[1][dc], qf[dc], st1, 0, 0, 0);
    }
    __builtin_amdgcn_s_setprio(0);

    // V fragments early (latency hides under exp/pack)
    bf16x8 vf0[4], vf1[4];
#pragma unroll
    for (int c = 0; c < 4; ++c) {
      int pos = 2 * c + hi;
      int r0 = l31, r1 = 32 + l31;
      vf0[c] = *(const bf16x8*)&Vs[cur][r0 * 64 + (pos ^ (r0 & 7)) * 8];
      vf1[c] = *(const bf16x8*)&Vs[cur][r1 * 64 + (pos ^ (r1 & 7)) * 8];
    }

    // P = exp2(S^T) in-register; accumulate per-lane partial row-sum
    float p0[16], p1[16];
    float ls = 0.f;
#pragma unroll
    for (int r = 0; r < 16; ++r) { p0[r] = fast_exp2(st0[r]); ls += p0[r]; }
#pragma unroll
    for (int r = 0; r < 16; ++r) { p1[r] = fast_exp2(st1[r]); ls += p1[r]; }
    lsum += ls;

    // pack to bf16 + permlane32_swap -> PV A-frags pa[c] (T12)
    bf16x8 pa[4];
#pragma unroll
    for (int f = 0; f < 2; ++f) {
      const float* pp = f ? p1 : p0;
#pragma unroll
      for (int cc = 0; cc < 2; ++cc) {
        unsigned uLO0 = cvt_pk_bf16(pp[8 * cc + 0], pp[8 * cc + 1]);
        unsigned uLO1 = cvt_pk_bf16(pp[8 * cc + 2], pp[8 * cc + 3]);
        unsigned uHI0 = cvt_pk_bf16(pp[8 * cc + 4], pp[8 * cc + 5]);
        unsigned uHI1 = cvt_pk_bf16(pp[8 * cc + 6], pp[8 * cc + 7]);
        auto s0 = __builtin_amdgcn_permlane32_swap(uLO0, uHI0, false, false);
        auto s1 = __builtin_amdgcn_permlane32_swap(uLO1, uHI1, false, false);
        union { unsigned u[4]; bf16x8 v; } pw;
        pw.u[0] = s0[0]; pw.u[1] = s1[0]; pw.u[2] = s0[1]; pw.u[3] = s1[1];
        pa[f * 2 + cc] = pw.v;
      }
    }

    // PV
    __builtin_amdgcn_s_setprio(1);
#pragma unroll
    for (int c = 0; c < 4; ++c) {
      o0 = __builtin_amdgcn_mfma_f32_32x32x16_bf16(pa[c], vf0[c], o0, 0, 0, 0);
      o1 = __builtin_amdgcn_mfma_f32_32x32x16_bf16(pa[c], vf1[c], o1, 0, 0, 0);
    }
    __builtin_amdgcn_s_setprio(0);

    asm volatile("" ::: "memory");
    __builtin_amdgcn_sched_barrier(0);
    __builtin_amdgcn_s_barrier();   // all reads of tile t done -> next stage may overwrite
    cur ^= 1;
  }

  // finalize: one cross-half reduce for li, broadcast 1/li per C-row, store
  lsum += __shfl_xor(lsum, 32);
  float inv = 1.f / lsum;  // valid for q = l31 (both halves)
#pragma unroll
  for (int r = 0; r < 16; ++r) {
    int qr = (r & 3) + 8 * (r >> 2) + 4 * hi;
    float ir = __shfl(inv, qr + (lane & 32));
    size_t row = q0 + w * 32 + qr;
    Aout[row * DIM + h * HD + l31]      = f2bf(o0[r] * ir);
    Aout[row * DIM + h * HD + 32 + l31] = f2bf(o1[r] * ir);
  }
}

extern "C" void kernel_launch(void* const* d_in, const int* in_sizes, int n_in,
                              void* d_out, int out_size, void* d_ws, size_t ws_size,
                              hipStream_t stream) {
  (void)in_sizes; (void)n_in; (void)out_size; (void)ws_size;
  const float* X  = (const float*)d_in[0];
  const float* wq = (const float*)d_in[1];
  const float* bq = (const float*)d_in[2];
  const float* wk = (const float*)d_in[3];
  const float* wv = (const float*)d_in[4];
  const float* bv = (const float*)d_in[5];
  const float* wo = (const float*)d_in[6];
  const float* bo = (const float*)d_in[7];

  char* ws = (char*)d_ws;
  const size_t SZ_XD  = (size_t)SEQ * DIM * 2;      // 8 MB
  const size_t SZ_W   = (size_t)DIM * DIM * 2;      // 2 MB
  const size_t SZ_QKV = (size_t)SEQ * QKVSTR * 2;   // 24 MB
  unsigned short* Xb   = (unsigned short*)(ws);                    // reused as Ab
  unsigned short* Wqkv = (unsigned short*)(ws + SZ_XD);            // [3072][1024]
  unsigned short* Wob  = (unsigned short*)(ws + SZ_XD + 3 * SZ_W);
  unsigned short* QKVb = (unsigned short*)(ws + SZ_XD + 4 * SZ_W); // [4096][3072]
  unsigned short* Vtb  = (unsigned short*)(ws + SZ_XD + 4 * SZ_W + SZ_QKV);
  unsigned short* Ab   = Xb;

  const float QSCALE = 0.125f * 1.44269504088896f;  // fold 1/sqrt(hd) * log2(e) into Wq/bq

  // one fused cast launch: 1048576 groups of 8 -> 4096 blocks
  cast_all_kernel<<<4096, 256, 0, stream>>>(X, wq, wk, wv, wo, Xb, Wqkv, Wob, QSCALE);

  // fused QKV projection: [4096][3072] bf16
  gemm_bt_kernel<1, 0><<<dim3(QKVSTR / 128, SEQ / 128), 256, 0, stream>>>(
      Xb, Wqkv, bq, bv, QSCALE, QKVb, SEQ, QKVSTR, DIM);

  // V^T: [1024][4096]
  transpose_kernel<<<dim3(SEQ / 64, DIM / 64), 256, 0, stream>>>(QKVb + 2 * DIM, Vtb);

  attn_kernel<<<SEQ / 128 * NH, 256, 0, stream>>>(QKVb, Vtb, Ab);

  // output projection (f32 out)
  gemm_bt_kernel<2, 1><<<dim3(DIM / 128, SEQ / 128), 256, 0, stream>>>(
      Ab, Wob, bo, nullptr, 1.f, d_out, SEQ, DIM, DIM);
}